// Round 6
// baseline (227.785 us; speedup 1.0000x reference)
//
#include <hip/hip_runtime.h>
#include <hip/hip_bf16.h>
#include <hip/hip_fp16.h>
#include <math.h>

// Problem: h = z @ W + b  (z [N,256] fp32, W [256,256] fp32, b [256])
//          out[e] = sigmoid(dot(h[src[e]], h[dst[e]]))  for E edges
// N = 100000, E = 300000, D = 256.
//
// R18: store-FIFO theory. All prior variants (62us invariant) issue each
// tile's A-loads BEHIND the previous tile's h-stores in the per-wave
// vmcnt FIFO; vmcnt retires in issue order, so load-waits transitively
// wait for store ACKS (slow: write drain measured 0.82 TB/s). Fix:
// rotate the persistent strip loop to [cvt-all(s) | loads(s+1) | pin |
// MFMA(s) | stores(s)] so loads are always OLDER than stores and retire
// first; store acks never block. Also: pack_w merged into the gemm
// prologue (each block packs W fp32->fp16 frags directly into LDS;
// kills a dispatch + launch gap + the g_Wf global round-trip).
// 256 persistent blocks x 512 thr, B resident in LDS (128KB), no
// barriers after the single post-pack __syncthreads.

#define D_DIM 256

typedef __attribute__((ext_vector_type(8))) _Float16 half8;
typedef __attribute__((ext_vector_type(4))) float f32x4;

__global__ __launch_bounds__(512, 2) void gemm_mfma_kernel(
    const float* __restrict__ z, const float* __restrict__ W,
    const float* __restrict__ b, __half* __restrict__ h, int nrows) {
  // 128KB resident B frags + 8 x 2176B per-wave epilogue tiles = 145KB
  __shared__ char smem[131072 + 8 * 2176];
  const int tid = threadIdx.x;
  const int lane = tid & 63;
  const int wv = tid >> 6;          // 0..7
  const int fr = lane & 15;
  const int qd = lane >> 4;

  // ---- pack W fp32 -> fp16 frags [kb][fn][qd][fr] directly into LDS.
  // frag(kb,fn,qd,fr)[j] = W[kb*32+qd*8+j][fn*16+fr]
  {
    __half* lp = (__half*)smem;
    const float4* W4 = (const float4*)W;
#pragma unroll 8
    for (int i = 0; i < 32; i++) {
      int q = i * 512 + tid;        // float4 idx 0..16383, coalesced
      int k = q >> 6;               // W row 0..255
      int n0 = (q & 63) * 4;        // W col base
      float4 w = W4[q];
      int kb = k >> 5, kqd = (k >> 3) & 3, j = k & 7;
#pragma unroll
      for (int u = 0; u < 4; u++) {
        int n = n0 + u;
        int fi = kb * 1024 + (n >> 4) * 64 + kqd * 16 + (n & 15);
        lp[fi * 8 + j] = __float2half(((const float*)&w)[u]);
      }
    }
  }
  float bias[16];
#pragma unroll
  for (int fn = 0; fn < 16; fn++) bias[fn] = b[fn * 16 + fr];

  __syncthreads();   // the ONLY barrier: B resident & read-only hereafter

  const half8* bw = (const half8*)smem;          // [kb*1024 + fn*64 + lane]
  __half* et = (__half*)(smem + 131072 + wv * 2176);  // 8 x 136 halves

  const int gw = blockIdx.x * 8 + wv;            // 0..2047
  const int nstrips = (nrows + 15) >> 4;         // 6250

  int r0 = gw * 16 + fr;
  r0 = r0 < nrows ? r0 : (nrows - 1);
  const float* zr0 = z + (size_t)r0 * D_DIM + qd * 8;

  // preload strip gw
  float4 a0[8], a1[8];
#pragma unroll
  for (int kb = 0; kb < 8; kb++) {
    a0[kb] = *(const float4*)(zr0 + kb * 32);
    a1[kb] = *(const float4*)(zr0 + kb * 32 + 4);
  }
  asm volatile("" ::: "memory");

#pragma unroll 1
  for (int s = gw; s < nstrips; s += 2048) {
    // ---- phase 1: convert this strip's A to fp16 frags (frees a0/a1)
    half8 af[8];
#pragma unroll
    for (int kb = 0; kb < 8; kb++) {
      af[kb][0] = (_Float16)a0[kb].x; af[kb][1] = (_Float16)a0[kb].y;
      af[kb][2] = (_Float16)a0[kb].z; af[kb][3] = (_Float16)a0[kb].w;
      af[kb][4] = (_Float16)a1[kb].x; af[kb][5] = (_Float16)a1[kb].y;
      af[kb][6] = (_Float16)a1[kb].z; af[kb][7] = (_Float16)a1[kb].w;
    }

    // ---- phase 2: issue NEXT strip's loads (BEFORE this strip's stores
    // so they are older in the vmcnt FIFO and retire independently).
    int snext = s + 2048;
    if (snext < nstrips) {
      int rn = snext * 16 + fr;
      rn = rn < nrows ? rn : (nrows - 1);
      const float* zrn = z + (size_t)rn * D_DIM + qd * 8;
#pragma unroll
      for (int kb = 0; kb < 8; kb++) {
        a0[kb] = *(const float4*)(zrn + kb * 32);
        a1[kb] = *(const float4*)(zrn + kb * 32 + 4);
      }
    }
    asm volatile("" ::: "memory");   // pin: loads issued here, not sunk

    // ---- phase 3: MFMA over resident B (LDS), latency cover for loads
    f32x4 acc[16];
#pragma unroll
    for (int fn = 0; fn < 16; fn++) acc[fn] = (f32x4)0.f;
#pragma unroll
    for (int kb = 0; kb < 8; kb++)
#pragma unroll
      for (int fn = 0; fn < 16; fn++) {
        half8 bf = bw[kb * 1024 + fn * 64 + lane];   // contiguous 1KB/wave
        acc[fn] = __builtin_amdgcn_mfma_f32_16x16x32_f16(af[kb], bf, acc[fn], 0, 0, 0);
      }

    // ---- phase 4: epilogue via wave-private LDS tile, then stores.
#pragma unroll
    for (int ph = 0; ph < 2; ph++) {
#pragma unroll
      for (int ch = 0; ch < 2; ch++) {
        if ((qd >> 1) == ph) {
#pragma unroll
          for (int f2 = 0; f2 < 8; f2++) {
            int fn = ch * 8 + f2;
#pragma unroll
            for (int rr = 0; rr < 4; rr++)
              et[((qd & 1) * 4 + rr) * 136 + f2 * 16 + fr] =
                  __float2half(acc[fn][rr] + bias[fn]);
          }
        }
#pragma unroll
        for (int p = 0; p < 2; p++) {
          int idx = p * 64 + lane;     // 0..127
          int rr = idx >> 4;           // 0..7
          int cc = idx & 15;           // 16B chunk within 128-col half
          float4 v = *(const float4*)(et + rr * 136 + cc * 8);
          int row = s * 16 + ph * 8 + rr;
          if (row < nrows)
            *(float4*)(h + (size_t)row * D_DIM + ch * 128 + cc * 8) = v;
        }
      }
    }
  }
}

// 1 wave per 8 edges; per edge ONE 1KB load instr: lanes 0-31 cover the
// 512B src row, lanes 32-63 the dst row. Pair via shfl_xor(32), butterfly.
__global__ __launch_bounds__(256) void edge_dot_kernel(
    const int* __restrict__ ei, const __half* __restrict__ h,
    float* __restrict__ out, int E) {
  int wid = (blockIdx.x * blockDim.x + threadIdx.x) >> 6;
  int lane = threadIdx.x & 63;
  int ebase = wid * 8;
  if (ebase >= E) return;
  const int half = lane >> 5;      // 0=src row, 1=dst row
  const int off = lane & 31;       // float4 chunk within the 512B row

  float4 v[8];
#pragma unroll
  for (int q = 0; q < 8; q++) {
    int e = ebase + q;
    e = e < E ? e : (E - 1);
    int node = half ? ei[E + e] : ei[e];   // uniform per 32-lane half
    v[q] = *(const float4*)((const __half*)h + (size_t)node * D_DIM + off * 8);
  }

  float res = 0.f;
#pragma unroll
  for (int q = 0; q < 8; q++) {
    float4 w;
    w.x = __shfl_xor(v[q].x, 32);
    w.y = __shfl_xor(v[q].y, 32);
    w.z = __shfl_xor(v[q].z, 32);
    w.w = __shfl_xor(v[q].w, 32);
    const __half2* a2 = (const __half2*)&v[q];
    const __half2* b2 = (const __half2*)&w;
    float part = 0.f;
#pragma unroll
    for (int j = 0; j < 4; j++) {
      float2 fa = __half22float2(a2[j]);
      float2 fb = __half22float2(b2[j]);
      part += fa.x * fb.x + fa.y * fb.y;
    }
#pragma unroll
    for (int m = 1; m <= 16; m <<= 1) part += __shfl_xor(part, m);
    res = (lane == q) ? part : res;    // lanes 0..7 collect the 8 results
  }
  if (lane < 8) {
    int e = ebase + lane;
    if (e < E) out[e] = 1.0f / (1.0f + __expf(-res));
  }
}

extern "C" void kernel_launch(void* const* d_in, const int* in_sizes, int n_in,
                              void* d_out, int out_size, void* d_ws, size_t ws_size,
                              hipStream_t stream) {
  const float* z  = (const float*)d_in[0];
  const int*   ei = (const int*)d_in[1];
  const float* W  = (const float*)d_in[2];
  const float* b  = (const float*)d_in[3];
  float* out = (float*)d_out;
  __half* h  = (__half*)d_ws;   // 100000*256*2 = 51.2 MB scratch

  const int nnodes = in_sizes[0] / D_DIM;
  const int E = in_sizes[1] / 2;

  gemm_mfma_kernel<<<256, 512, 0, stream>>>(z, W, b, h, nnodes);

  int waves = (E + 7) / 8;                        // 1 wave per 8 edges
  dim3 grid_edge(((size_t)waves * 64 + 255) / 256);
  edge_dot_kernel<<<grid_edge, 256, 0, stream>>>(ei, h, out, E);
}

// Round 7
// 202.352 us; speedup vs baseline: 1.1257x; 1.1257x over previous
//
#include <hip/hip_runtime.h>
#include <hip/hip_bf16.h>
#include <hip/hip_fp16.h>
#include <math.h>

// Problem: h = z @ W + b  (z [N,256] fp32, W [256,256] fp32, b [256])
//          out[e] = sigmoid(dot(h[src[e]], h[dst[e]]))  for E edges
// N = 100000, E = 300000, D = 256.
//
// R19: DRAM-contiguity fix. All prior variants loaded A with each
// instruction touching 16 rows 1KB apart (16 DRAM pages interleaved
// 16x per strip) -> 1.65 TB/s vs m13-copy's 6.29 TB/s contiguous.
// Five scheduling theories died (barrier drain / counted vmcnt /
// occupancy / request count / store FIFO) because the inefficiency is
// access-pattern-level, invariant under scheduling. Now: 256 persistent
// blocks, B resident in LDS (128KB, R17 staging); per 16-row strip the
// BLOCK loads z LINEARLY (every instruction 1KB-contiguous), cvt fp32->
// fp16 in regs, ds_write to XOR-swizzled A-tile (stride-512 16-way ->
// 2-way), MFMA reads frags from LDS. Wave n-split (cols wv*32..+31,
// acc = 8 VGPR). A dbuf 2x8KB; epilogue aliases the consumed tile
// (own-region, same-wave ordering). 2 plain __syncthreads per strip.

#define D_DIM 256
#define NBLK 256

typedef __attribute__((ext_vector_type(8))) _Float16 half8;
typedef __attribute__((ext_vector_type(4))) _Float16 half4;
typedef __attribute__((ext_vector_type(4))) float f32x4;

__device__ half8 g_Wf[8 * 256 * 4];   // [kb][fn][qd][fr], 128 KB

// 8192 threads: t -> (kb, qd, n), n fastest => coalesced row reads of W.
// frag(n = fn*16+fr, qd)[j] = W[(kb*32 + qd*8 + j)*256 + n]
__global__ __launch_bounds__(256) void pack_w_kernel(const float* __restrict__ W) {
  int t = blockIdx.x * 256 + threadIdx.x;   // 0..8191
  int kb = t >> 10;
  int qd = (t >> 8) & 3;
  int n  = t & 255;
  int fn = n >> 4;
  int fr = n & 15;
  half8 o;
#pragma unroll
  for (int j = 0; j < 8; j++)
    o[j] = (_Float16)W[(size_t)(kb * 32 + qd * 8 + j) * D_DIM + n];
  g_Wf[kb * 1024 + fn * 64 + qd * 16 + fr] = o;
}

// cvt two float4 (fp32 z data) and ds_write as fp16 into swizzled A-tile.
// Thread t covers z-strip fp32 elems [t*4 .. t*4+4) (row t>>6) and
// [2048 + t*4 ..) (row (t>>6)+8). Swizzle: phys = row*512 + (inner ^
// ((row&7)<<4)); rows r and r+8 share (row&7) -> same XOR.
__device__ inline void stage_write(char* tile, int tid, float4 A, float4 B) {
  int row = tid >> 6;                 // 0..7
  int inner = (tid & 63) * 8;         // byte offset in 512B fp16 row
  int sw = (row & 7) << 4;
  half4 p0, p1;
  p0[0] = (_Float16)A.x; p0[1] = (_Float16)A.y;
  p0[2] = (_Float16)A.z; p0[3] = (_Float16)A.w;
  p1[0] = (_Float16)B.x; p1[1] = (_Float16)B.y;
  p1[2] = (_Float16)B.z; p1[3] = (_Float16)B.w;
  *(half4*)(tile + row * 512 + (inner ^ sw)) = p0;
  *(half4*)(tile + (row + 8) * 512 + (inner ^ sw)) = p1;
}

__global__ __launch_bounds__(512) void gemm_mfma_kernel(
    const float* __restrict__ z, const float* __restrict__ b,
    __half* __restrict__ h, int nrows) {
  // 128KB resident B frags + 2 x 8KB A-tile double buffer = 144KB.
  __shared__ char smem[147456];
  const int tid = threadIdx.x;
  const int lane = tid & 63;
  const int wv = tid >> 6;          // 0..7 (owns cols wv*32 .. +31)
  const int fr = lane & 15;
  const int qd = lane >> 4;

  // ---- one-time B stage: linear 128KB via global_load_lds (R17, clean)
  {
    const char* gsrc = (const char*)g_Wf;
#pragma unroll
    for (int rnd = 0; rnd < 16; rnd++) {
      int off = rnd * 8192 + wv * 1024;
      __builtin_amdgcn_global_load_lds(
          (const __attribute__((address_space(1))) void*)(gsrc + off + lane * 16),
          (__attribute__((address_space(3))) void*)(smem + off),
          16, 0, 0);
    }
  }
  float bias0 = b[wv * 32 + fr];
  float bias1 = b[wv * 32 + 16 + fr];

  char* atile0 = smem + 131072;
  char* atile1 = smem + 139264;
  const char* zb = (const char*)z;
  const int nstrips = (nrows + 15) >> 4;   // 6250 (N%16==0 here)

  // ---- prologue: stage strip s0 into atile0 (linear loads, 1KB/instr)
  int s0 = blockIdx.x;
  float4 ld0, ld1;
  {
    const char* sb = zb + (size_t)s0 * 16384;
    ld0 = *(const float4*)(sb + tid * 16);
    ld1 = *(const float4*)(sb + 8192 + tid * 16);
  }
  stage_write(atile0, tid, ld0, ld1);
  __syncthreads();   // B + A(s0) resident & visible

  const half8* bw = (const half8*)smem;
  int cur = 0;

#pragma unroll 1
  for (int s = s0; s < nstrips; s += NBLK) {
    char* at = cur ? atile1 : atile0;
    char* an = cur ? atile0 : atile1;
    const bool hasnext = (s + NBLK) < nstrips;

    // issue next strip's loads (contiguous; consumed after epilogue)
    if (hasnext) {
      const char* sb = zb + (size_t)(s + NBLK) * 16384;
      ld0 = *(const float4*)(sb + tid * 16);
      ld1 = *(const float4*)(sb + 8192 + tid * 16);
    }
    asm volatile("" ::: "memory");   // pin issue point (R13 lesson)

    // ---- MFMA: af from swizzled A-tile, bf from resident B
    f32x4 acc0 = (f32x4)0.f, acc1 = (f32x4)0.f;
    const char* abase = at + fr * 512;
    const int sw = (fr & 7) << 4;
#pragma unroll
    for (int kb = 0; kb < 8; kb++) {
      half8 af = *(const half8*)(abase + ((kb * 64 + qd * 16) ^ sw));
      half8 bf0 = bw[kb * 1024 + (2 * wv) * 64 + lane];
      half8 bf1 = bw[kb * 1024 + (2 * wv + 1) * 64 + lane];
      acc0 = __builtin_amdgcn_mfma_f32_16x16x32_f16(af, bf0, acc0, 0, 0, 0);
      acc1 = __builtin_amdgcn_mfma_f32_16x16x32_f16(af, bf1, acc1, 0, 0, 0);
    }
    __syncthreads();   // all waves done reading at -> safe to reuse

    // ---- epilogue: own 1KB region of the consumed tile (rows 16 x 64B)
    __half* et = (__half*)(at + wv * 1024);
#pragma unroll
    for (int r = 0; r < 4; r++) {
      et[(qd * 4 + r) * 32 + fr]      = __float2half(acc0[r] + bias0);
      et[(qd * 4 + r) * 32 + 16 + fr] = __float2half(acc1[r] + bias1);
    }
    int row = lane >> 2, c = lane & 3;
    float4 v = *(const float4*)((const char*)et + row * 64 + c * 16);

    // consume next loads into the other tile (latency covered by MFMA+epi)
    if (hasnext) stage_write(an, tid, ld0, ld1);

    // coalesced 64B-chunk store of own column slice (fire & forget)
    int grow = s * 16 + row;
    if (grow < nrows)
      *(float4*)((char*)h + (size_t)grow * 512 + wv * 64 + c * 16) = v;

    cur ^= 1;
    __syncthreads();   // next iter's tile staged & visible; epi reads done
  }
}

// 1 wave per 8 edges; per edge ONE 1KB load instr: lanes 0-31 cover the
// 512B src row, lanes 32-63 the dst row. Pair via shfl_xor(32), butterfly.
__global__ __launch_bounds__(256) void edge_dot_kernel(
    const int* __restrict__ ei, const __half* __restrict__ h,
    float* __restrict__ out, int E) {
  int wid = (blockIdx.x * blockDim.x + threadIdx.x) >> 6;
  int lane = threadIdx.x & 63;
  int ebase = wid * 8;
  if (ebase >= E) return;
  const int half = lane >> 5;      // 0=src row, 1=dst row
  const int off = lane & 31;       // float4 chunk within the 512B row

  float4 v[8];
#pragma unroll
  for (int q = 0; q < 8; q++) {
    int e = ebase + q;
    e = e < E ? e : (E - 1);
    int node = half ? ei[E + e] : ei[e];   // uniform per 32-lane half
    v[q] = *(const float4*)((const __half*)h + (size_t)node * D_DIM + off * 8);
  }

  float res = 0.f;
#pragma unroll
  for (int q = 0; q < 8; q++) {
    float4 w;
    w.x = __shfl_xor(v[q].x, 32);
    w.y = __shfl_xor(v[q].y, 32);
    w.z = __shfl_xor(v[q].z, 32);
    w.w = __shfl_xor(v[q].w, 32);
    const __half2* a2 = (const __half2*)&v[q];
    const __half2* b2 = (const __half2*)&w;
    float part = 0.f;
#pragma unroll
    for (int j = 0; j < 4; j++) {
      float2 fa = __half22float2(a2[j]);
      float2 fb = __half22float2(b2[j]);
      part += fa.x * fb.x + fa.y * fb.y;
    }
#pragma unroll
    for (int m = 1; m <= 16; m <<= 1) part += __shfl_xor(part, m);
    res = (lane == q) ? part : res;    // lanes 0..7 collect the 8 results
  }
  if (lane < 8) {
    int e = ebase + lane;
    if (e < E) out[e] = 1.0f / (1.0f + __expf(-res));
  }
}

extern "C" void kernel_launch(void* const* d_in, const int* in_sizes, int n_in,
                              void* d_out, int out_size, void* d_ws, size_t ws_size,
                              hipStream_t stream) {
  const float* z  = (const float*)d_in[0];
  const int*   ei = (const int*)d_in[1];
  const float* W  = (const float*)d_in[2];
  const float* b  = (const float*)d_in[3];
  float* out = (float*)d_out;
  __half* h  = (__half*)d_ws;   // 100000*256*2 = 51.2 MB scratch

  const int nnodes = in_sizes[0] / D_DIM;
  const int E = in_sizes[1] / 2;

  pack_w_kernel<<<32, 256, 0, stream>>>(W);

  gemm_mfma_kernel<<<NBLK, 512, 0, stream>>>(z, b, h, nnodes);

  int waves = (E + 7) / 8;                        // 1 wave per 8 edges
  dim3 grid_edge(((size_t)waves * 64 + 255) / 256);
  edge_dot_kernel<<<grid_edge, 256, 0, stream>>>(ei, h, out, E);
}